// Round 9
// baseline (97.134 us; speedup 1.0000x reference)
//
#include <hip/hip_runtime.h>

#define B 16
#define N 1024
#define M 1024
#define TN 8
#define BPB (N / TN)             // 128 blocks per batch entry
#define NBLK (B * BPB)           // 2048 blocks
#define C2 64                    // band capacity per block

// ws float-index layout
#define WS_CNTB  0               // per-b done counters (uint), stride 16 floats, b*16
#define WS_CNTF  256             // final counter (uint)
#define WS_RES   320             // per-b {sw, sc, se, cn, pose}, stride 8
#define WS_PMAX  512             // per-block max, NBLK -> 512..2559
#define WS_BCNT  2560            // per-block band count (uint), NBLK -> 2560..4607
#define WS_PACC  4608            // per-block {sum_w,sum_cw,sum_ew,count} float4, NBLK (16B aligned)
#define WS_BAND  12800           // per-block band triples {w, w*ce, w*ee}, NBLK*C2*3

#define NEG_INF (-3.402823466e+38f)

// F row-major: F[i*3+l] = F[i][l];  F = K^-T E K^-1, E = skew(t_n) R_gt
__device__ __forceinline__ void compute_F(const float* __restrict__ Rgp,
                                          const float* __restrict__ tg,
                                          const float* __restrict__ Km,
                                          float* F)
{
    float m00=Km[0], m01=Km[1], m02=Km[2];
    float m10=Km[3], m11=Km[4], m12=Km[5];
    float m20=Km[6], m21=Km[7], m22=Km[8];
    float c00 =  (m11*m22 - m12*m21), c01 = -(m10*m22 - m12*m20), c02 =  (m10*m21 - m11*m20);
    float c10 = -(m01*m22 - m02*m21), c11 =  (m00*m22 - m02*m20), c12 = -(m00*m21 - m01*m20);
    float c20 =  (m01*m12 - m02*m11), c21 = -(m00*m12 - m02*m10), c22 =  (m00*m11 - m01*m10);
    float id  = 1.f / (m00*c00 + m01*c01 + m02*c02);
    float Ki00 = c00*id, Ki01 = c10*id, Ki02 = c20*id;
    float Ki10 = c01*id, Ki11 = c11*id, Ki12 = c21*id;
    float Ki20 = c02*id, Ki21 = c12*id, Ki22 = c22*id;
    float inr = rsqrtf(tg[0]*tg[0] + tg[1]*tg[1] + tg[2]*tg[2]);
    float tx = tg[0]*inr, ty = tg[1]*inr, tz = tg[2]*inr;
    float Rg0=Rgp[0],Rg1=Rgp[1],Rg2=Rgp[2],Rg3=Rgp[3],Rg4=Rgp[4],Rg5=Rgp[5],Rg6=Rgp[6],Rg7=Rgp[7],Rg8=Rgp[8];
    float E00=-tz*Rg3+ty*Rg6, E01=-tz*Rg4+ty*Rg7, E02=-tz*Rg5+ty*Rg8;
    float E10= tz*Rg0-tx*Rg6, E11= tz*Rg1-tx*Rg7, E12= tz*Rg2-tx*Rg8;
    float E20=-ty*Rg0+tx*Rg3, E21=-ty*Rg1+tx*Rg4, E22=-ty*Rg2+tx*Rg5;
    float T00=E00*Ki00+E01*Ki10+E02*Ki20, T01=E00*Ki01+E01*Ki11+E02*Ki21, T02=E00*Ki02+E01*Ki12+E02*Ki22;
    float T10=E10*Ki00+E11*Ki10+E12*Ki20, T11=E10*Ki01+E11*Ki11+E12*Ki21, T12=E10*Ki02+E11*Ki12+E12*Ki22;
    float T20=E20*Ki00+E21*Ki10+E22*Ki20, T21=E20*Ki01+E21*Ki11+E22*Ki21, T22=E20*Ki02+E21*Ki12+E22*Ki22;
    F[0]=Ki00*T00+Ki10*T10+Ki20*T20; F[1]=Ki00*T01+Ki10*T11+Ki20*T21; F[2]=Ki00*T02+Ki10*T12+Ki20*T22;
    F[3]=Ki01*T00+Ki11*T10+Ki21*T20; F[4]=Ki01*T01+Ki11*T11+Ki21*T21; F[5]=Ki01*T02+Ki11*T12+Ki21*T22;
    F[6]=Ki02*T00+Ki12*T10+Ki22*T20; F[7]=Ki02*T01+Ki12*T11+Ki22*T21; F[8]=Ki02*T02+Ki12*T12+Ki22*T22;
}

__launch_bounds__(256, 4)
__global__ void k_fused(const float* __restrict__ matches,
                        const float* __restrict__ R_pred, const float* __restrict__ t_pred,
                        const float* __restrict__ R_gt,   const float* __restrict__ t_gt,
                        const float* __restrict__ Kin,
                        const float* __restrict__ kp1,    const float* __restrict__ kp2,
                        float* __restrict__ ws, float* __restrict__ out)
{
    const int bid  = blockIdx.x;
    const int b    = bid >> 7;           // BPB = 128
    const int row0 = (bid & 127) * TN;
    const int t    = threadIdx.x;
    const int lane = t & 63, wv = t >> 6;

    __shared__ float4 sTP[TN];
    __shared__ float  sm[4];
    __shared__ float4 paccL[4];
    __shared__ int    wtot[4];
    __shared__ int    sFin;

    // =============== streaming phase (identical structure to round-7 k1) ===============
    {
        // issue all 8 matches loads first (32 VGPRs in flight)
        const float4* m4 = (const float4*)matches + ((long)b * N + row0) * (M/4) + t;
        float4 d[TN];
        #pragma unroll
        for (int n = 0; n < TN; ++n) d[n] = m4[n * (M/4)];

        // per-row broadcast: T = (R_gt @ homo(kp1))[:2] and kp1
        const float* Rgp = R_gt + b * 9;
        if (t < TN) {
            float2 p = ((const float2*)kp1)[(long)b * N + row0 + t];
            sTP[t] = make_float4(Rgp[0]*p.x + Rgp[1]*p.y + Rgp[2],
                                 Rgp[3]*p.x + Rgp[4]*p.y + Rgp[5], p.x, p.y);
        }

        // fundamental matrix + per-column factors (overlaps load latency)
        float F[9];
        compute_F(Rgp, t_gt + b*3, Kin + b*9, F);
        const float4* kp2v = (const float4*)(kp2 + (long)b * M * 2);
        float4 q0 = kp2v[2*t], q1 = kp2v[2*t + 1];
        float k2x[4] = {q0.x, q0.z, q1.x, q1.z};
        float k2y[4] = {q0.y, q0.w, q1.y, q1.w};
        float A0[4], A1[4], A2[4];
        #pragma unroll
        for (int j = 0; j < 4; ++j) {
            A0[j] = k2x[j]*F[0] + k2y[j]*F[3] + F[6];
            A1[j] = k2x[j]*F[1] + k2y[j]*F[4] + F[7];
            A2[j] = k2x[j]*F[2] + k2y[j]*F[5] + F[8];
        }
        __syncthreads();   // sTP ready

        // block max
        float v = NEG_INF;
        #pragma unroll
        for (int n = 0; n < TN; ++n)
            v = fmaxf(v, fmaxf(fmaxf(d[n].x, d[n].y), fmaxf(d[n].z, d[n].w)));
        #pragma unroll
        for (int off = 32; off; off >>= 1) v = fmaxf(v, __shfl_down(v, off));
        if (lane == 0) sm[wv] = v;
        __syncthreads();
        float bmax = fmaxf(fmaxf(sm[0], sm[1]), fmaxf(sm[2], sm[3]));
        if (t == 0) ws[WS_PMAX + bid] = bmax;
        float thr_b = 0.1f * bmax;
        float cap_b = 1.01f * thr_b;

        // sums at local threshold + band count
        float s_w = 0.f, s_c = 0.f, s_e = 0.f, s_n = 0.f;
        int bcnt = 0;
        #pragma unroll
        for (int n = 0; n < TN; ++n) {
            float4 tp = sTP[n];
            float mv[4] = {d[n].x, d[n].y, d[n].z, d[n].w};
            #pragma unroll
            for (int j = 0; j < 4; ++j) {
                float w = mv[j];
                bool pass = w > thr_b;
                float ww = pass ? w : 0.f;
                s_n += pass ? 1.f : 0.f;
                bcnt += (pass && w <= cap_b) ? 1 : 0;
                float dx = k2x[j] - tp.x, dy = k2y[j] - tp.y;
                float ce = sqrtf(dx*dx + dy*dy);
                float ee = fabsf(A0[j]*tp.z + A1[j]*tp.w + A2[j]);
                s_w += ww; s_c += ce*ww; s_e += ee*ww;
            }
        }
        // wave-reduce sums + wave-scan band count
        #pragma unroll
        for (int off = 32; off; off >>= 1) {
            s_w += __shfl_down(s_w, off);
            s_c += __shfl_down(s_c, off);
            s_e += __shfl_down(s_e, off);
            s_n += __shfl_down(s_n, off);
        }
        int incl = bcnt;
        #pragma unroll
        for (int off = 1; off < 64; off <<= 1) {
            int y = __shfl_up(incl, off);
            if (lane >= off) incl += y;
        }
        if (lane == 0)  paccL[wv] = make_float4(s_w, s_c, s_e, s_n);
        if (lane == 63) wtot[wv] = incl;
        __syncthreads();
        if (t == 0) {
            float4 r = paccL[0];
            #pragma unroll
            for (int i = 1; i < 4; ++i) { r.x += paccL[i].x; r.y += paccL[i].y; r.z += paccL[i].z; r.w += paccL[i].w; }
            ((float4*)(ws + WS_PACC))[bid] = r;
        }
        int pos = incl - bcnt;
        #pragma unroll
        for (int k = 0; k < 4; ++k) if (k < wv) pos += wtot[k];
        int total = wtot[0] + wtot[1] + wtot[2] + wtot[3];
        if (t == 0) ((unsigned int*)ws)[WS_BCNT + bid] = (unsigned int)total;

        if (total > 0 && total <= C2) {
            float* band = ws + WS_BAND + (long)bid * (C2 * 3);
            #pragma unroll
            for (int n = 0; n < TN; ++n) {
                float4 tp = sTP[n];
                float mv[4] = {d[n].x, d[n].y, d[n].z, d[n].w};
                #pragma unroll
                for (int j = 0; j < 4; ++j) {
                    float w = mv[j];
                    if (w > thr_b && w <= cap_b) {
                        float dx = k2x[j] - tp.x, dy = k2y[j] - tp.y;
                        float ce = sqrtf(dx*dx + dy*dy);
                        float ee = fabsf(A0[j]*tp.z + A1[j]*tp.w + A2[j]);
                        band[pos*3 + 0] = w;
                        band[pos*3 + 1] = ce * w;
                        band[pos*3 + 2] = ee * w;
                        ++pos;
                    }
                }
            }
        }
    }   // <- every streaming-phase register dies here

    // ---- completion: per-b counter (128 increments across 16 independent lines) ----
    __syncthreads();
    if (t == 0) {
        __threadfence();
        unsigned int old = atomicAdd(((unsigned int*)ws) + WS_CNTB + b * 16, 1u);
        sFin = (old == (unsigned int)(BPB - 1)) ? 1 : 0;
    }
    __syncthreads();
    if (!sFin) return;

    // ================= finisher for batch entry b (fully self-contained) =================
    __threadfence();   // acquire: see other blocks' PMAX/PACC/BCNT/BAND

    __shared__ float sThr;
    __shared__ float sAcc4[4];
    __shared__ int   sFlag[BPB];
    __shared__ int   sNFlag;
    __shared__ int   sLastF;
    if (t < 4) sAcc4[t] = 0.f;
    if (t == 0) sNFlag = 0;

    // phase A: true per-b threshold from 128 block maxes
    if (t < 64) {
        float pv = fmaxf(ws[WS_PMAX + b*BPB + t], ws[WS_PMAX + b*BPB + 64 + t]);
        #pragma unroll
        for (int off = 32; off; off >>= 1) pv = fmaxf(pv, __shfl_down(pv, off));
        if (t == 0) sThr = 0.1f * pv;
    }
    __syncthreads();
    const float thr = sThr;

    // phase B: 2 threads per bid, signed accumulate PACC - band corrections
    {
        int bidl = t >> 1;
        int half = t & 1;
        int bid2 = b*BPB + bidl;
        float s0 = 0.f, s1 = 0.f, s2 = 0.f, s3 = 0.f;
        float capb2 = 1.01f * 0.1f * ws[WS_PMAX + bid2];
        unsigned int bc = ((const unsigned int*)ws)[WS_BCNT + bid2];
        bool bad = (bc > (unsigned)C2) || (thr > capb2);
        if (!bad) {
            const float* band = ws + WS_BAND + (long)bid2 * (C2 * 3);
            for (unsigned int k = half; k < bc; k += 2) {
                float w = band[k*3 + 0];
                if (!(w > thr)) { s0 -= w; s1 -= band[k*3 + 1]; s2 -= band[k*3 + 2]; s3 -= 1.f; }
            }
            if (half == 0) {
                float4 p = ((const float4*)(ws + WS_PACC))[bid2];
                s0 += p.x; s1 += p.y; s2 += p.z; s3 += p.w;
            }
        } else if (half == 0) {
            int idx = atomicAdd(&sNFlag, 1);
            sFlag[idx] = bidl;
        }
        #pragma unroll
        for (int off = 32; off; off >>= 1) {
            s0 += __shfl_down(s0, off);
            s1 += __shfl_down(s1, off);
            s2 += __shfl_down(s2, off);
            s3 += __shfl_down(s3, off);
        }
        if (lane == 0) {
            atomicAdd(&sAcc4[0], s0);
            atomicAdd(&sAcc4[1], s1);
            atomicAdd(&sAcc4[2], s2);
            atomicAdd(&sAcc4[3], s3);
        }
    }
    __syncthreads();

    // phase C: guaranteed-correct reread of flagged tiles (normally 0) — recomputes everything
    const int nflag = sNFlag;
    for (int f = 0; f < nflag; ++f) {
        __syncthreads();
        const float* Rgp = R_gt + b * 9;
        int rrow0 = sFlag[f] * TN;
        if (t < TN) {
            float2 p = ((const float2*)kp1)[(long)b * N + rrow0 + t];
            sTP[t] = make_float4(Rgp[0]*p.x + Rgp[1]*p.y + Rgp[2],
                                 Rgp[3]*p.x + Rgp[4]*p.y + Rgp[5], p.x, p.y);
        }
        float F[9];
        compute_F(Rgp, t_gt + b*3, Kin + b*9, F);
        const float4* kp2v = (const float4*)(kp2 + (long)b * M * 2);
        float4 q0 = kp2v[2*t], q1 = kp2v[2*t + 1];
        float k2x[4] = {q0.x, q0.z, q1.x, q1.z};
        float k2y[4] = {q0.y, q0.w, q1.y, q1.w};
        float A0[4], A1[4], A2[4];
        #pragma unroll
        for (int j = 0; j < 4; ++j) {
            A0[j] = k2x[j]*F[0] + k2y[j]*F[3] + F[6];
            A1[j] = k2x[j]*F[1] + k2y[j]*F[4] + F[7];
            A2[j] = k2x[j]*F[2] + k2y[j]*F[5] + F[8];
        }
        const float4* m4r = (const float4*)matches + ((long)b * N + rrow0) * (M/4) + t;
        float4 dr[TN];
        #pragma unroll
        for (int n = 0; n < TN; ++n) dr[n] = m4r[n * (M/4)];
        __syncthreads();
        float s_w = 0.f, s_c = 0.f, s_e = 0.f, s_n = 0.f;
        #pragma unroll
        for (int n = 0; n < TN; ++n) {
            float4 tp = sTP[n];
            float mv[4] = {dr[n].x, dr[n].y, dr[n].z, dr[n].w};
            #pragma unroll
            for (int j = 0; j < 4; ++j) {
                float w = mv[j];
                bool pass = w > thr;
                float ww = pass ? w : 0.f;
                s_n += pass ? 1.f : 0.f;
                float dx = k2x[j] - tp.x, dy = k2y[j] - tp.y;
                float ce = sqrtf(dx*dx + dy*dy);
                float ee = fabsf(A0[j]*tp.z + A1[j]*tp.w + A2[j]);
                s_w += ww; s_c += ce*ww; s_e += ee*ww;
            }
        }
        #pragma unroll
        for (int off = 32; off; off >>= 1) {
            s_w += __shfl_down(s_w, off);
            s_c += __shfl_down(s_c, off);
            s_e += __shfl_down(s_e, off);
            s_n += __shfl_down(s_n, off);
        }
        if (lane == 0) {
            atomicAdd(&sAcc4[0], s_w);
            atomicAdd(&sAcc4[1], s_c);
            atomicAdd(&sAcc4[2], s_e);
            atomicAdd(&sAcc4[3], s_n);
        }
    }
    __syncthreads();

    // phase D: per-b pose + result; last finisher combines
    if (t == 0) {
        const float* Rp = R_pred + b * 9;
        const float* Rq = R_gt   + b * 9;
        float trace = 0.f;
        #pragma unroll
        for (int i = 0; i < 9; ++i) trace += Rp[i] * Rq[i];
        float geo = fminf(fmaxf((trace - 1.f) * 0.5f, -1.f + 1e-7f), 1.f - 1e-7f);
        const float* tq = t_gt   + b * 3;
        const float* tp = t_pred + b * 3;
        float in2 = rsqrtf(tq[0]*tq[0] + tq[1]*tq[1] + tq[2]*tq[2]);
        float dotp = (tp[0]*tq[0] + tp[1]*tq[1] + tp[2]*tq[2]) * in2;
        float* res = ws + WS_RES + b * 8;
        res[0] = sAcc4[0]; res[1] = sAcc4[1]; res[2] = sAcc4[2]; res[3] = sAcc4[3];
        res[4] = (1.f - geo) + (1.f - dotp);
        __threadfence();
        unsigned int old = atomicAdd(((unsigned int*)ws) + WS_CNTF, 1u);
        sLastF = (old == (unsigned int)(B - 1)) ? 1 : 0;
    }
    __syncthreads();
    if (!sLastF) return;

    if (t == 0) {
        __threadfence();
        float pose = 0.f, ms = 0.f, es = 0.f;
        int nv = 0;
        for (int bb = 0; bb < B; ++bb) {
            const float* res = ws + WS_RES + bb * 8;
            float sw = res[0], sc = res[1], se = res[2], cn = res[3];
            pose += res[4];
            if (cn >= 3.f) { nv++; ms += sc / (sw + 1e-8f); es += se / (sw + 1e-8f); }
        }
        float match = nv > 0 ? ms / (float)nv : 0.f;
        float epi   = nv > 0 ? es / (float)nv : 0.f;
        out[0] = pose * (1.f / (float)B) + 0.5f * match + 0.1f * epi;
    }
}

extern "C" void kernel_launch(void* const* d_in, const int* in_sizes, int n_in,
                              void* d_out, int out_size, void* d_ws, size_t ws_size,
                              hipStream_t stream) {
    const float* R_pred  = (const float*)d_in[0];
    const float* t_pred  = (const float*)d_in[1];
    const float* R_gt    = (const float*)d_in[2];
    const float* t_gt    = (const float*)d_in[3];
    const float* K       = (const float*)d_in[4];
    const float* kp1     = (const float*)d_in[5];
    const float* kp2     = (const float*)d_in[6];
    const float* matches = (const float*)d_in[7];
    float* out = (float*)d_out;
    float* ws  = (float*)d_ws;

    // zero the completion counters (cannot rely on ws state across calls)
    hipMemsetAsync(ws, 0, 2048, stream);
    k_fused<<<NBLK, 256, 0, stream>>>(matches, R_pred, t_pred, R_gt, t_gt,
                                      K, kp1, kp2, ws, out);
}

// Round 10
// 78.240 us; speedup vs baseline: 1.2415x; 1.2415x over previous
//
#include <hip/hip_runtime.h>

#define B 16
#define N 1024
#define M 1024
#define TN 8
#define BPB (N / TN)             // 128 blocks per batch entry
#define NBLK (B * BPB)           // 2048 blocks
#define CAP 4096                 // dense band capacity per batch entry

// ws float-index layout
#define WS_CNT   0               // per-b append counters (uint), stride 16 floats -> 0..255
#define WS_PMAX  256             // per-block max, NBLK -> 256..2303
#define WS_PACC  2304            // per-block {sum_w,sum_cw,sum_ew,count} float4, NBLK
#define WS_DENSE 10496           // per-b dense band lists, float4 entries, b*CAP

#define NEG_INF (-3.402823466e+38f)

// F row-major: F[i*3+l];  F = K^-T E K^-1, E = skew(t_n) R_gt
__device__ __forceinline__ void compute_F(const float* __restrict__ Rgp,
                                          const float* __restrict__ tg,
                                          const float* __restrict__ Km,
                                          float* F)
{
    float m00=Km[0], m01=Km[1], m02=Km[2];
    float m10=Km[3], m11=Km[4], m12=Km[5];
    float m20=Km[6], m21=Km[7], m22=Km[8];
    float c00 =  (m11*m22 - m12*m21), c01 = -(m10*m22 - m12*m20), c02 =  (m10*m21 - m11*m20);
    float c10 = -(m01*m22 - m02*m21), c11 =  (m00*m22 - m02*m20), c12 = -(m00*m21 - m01*m20);
    float c20 =  (m01*m12 - m02*m11), c21 = -(m00*m12 - m02*m10), c22 =  (m00*m11 - m01*m10);
    float id  = 1.f / (m00*c00 + m01*c01 + m02*c02);
    float Ki00 = c00*id, Ki01 = c10*id, Ki02 = c20*id;
    float Ki10 = c01*id, Ki11 = c11*id, Ki12 = c21*id;
    float Ki20 = c02*id, Ki21 = c12*id, Ki22 = c22*id;
    float inr = rsqrtf(tg[0]*tg[0] + tg[1]*tg[1] + tg[2]*tg[2]);
    float tx = tg[0]*inr, ty = tg[1]*inr, tz = tg[2]*inr;
    float Rg0=Rgp[0],Rg1=Rgp[1],Rg2=Rgp[2],Rg3=Rgp[3],Rg4=Rgp[4],Rg5=Rgp[5],Rg6=Rgp[6],Rg7=Rgp[7],Rg8=Rgp[8];
    float E00=-tz*Rg3+ty*Rg6, E01=-tz*Rg4+ty*Rg7, E02=-tz*Rg5+ty*Rg8;
    float E10= tz*Rg0-tx*Rg6, E11= tz*Rg1-tx*Rg7, E12= tz*Rg2-tx*Rg8;
    float E20=-ty*Rg0+tx*Rg3, E21=-ty*Rg1+tx*Rg4, E22=-ty*Rg2+tx*Rg5;
    float T00=E00*Ki00+E01*Ki10+E02*Ki20, T01=E00*Ki01+E01*Ki11+E02*Ki21, T02=E00*Ki02+E01*Ki12+E02*Ki22;
    float T10=E10*Ki00+E11*Ki10+E12*Ki20, T11=E10*Ki01+E11*Ki11+E12*Ki21, T12=E10*Ki02+E11*Ki12+E12*Ki22;
    float T20=E20*Ki00+E21*Ki10+E22*Ki20, T21=E20*Ki01+E21*Ki11+E22*Ki21, T22=E20*Ki02+E21*Ki12+E22*Ki22;
    F[0]=Ki00*T00+Ki10*T10+Ki20*T20; F[1]=Ki00*T01+Ki10*T11+Ki20*T21; F[2]=Ki00*T02+Ki10*T12+Ki20*T22;
    F[3]=Ki01*T00+Ki11*T10+Ki21*T20; F[4]=Ki01*T01+Ki11*T11+Ki21*T21; F[5]=Ki01*T02+Ki11*T12+Ki21*T22;
    F[6]=Ki02*T00+Ki12*T10+Ki22*T20; F[7]=Ki02*T01+Ki12*T11+Ki22*T21; F[8]=Ki02*T02+Ki12*T12+Ki22*T22;
}

// ---------- kernel 1: single full read of matches: max + local-thr sums + dense band append
__launch_bounds__(256, 4)
__global__ void k1_fused(const float* __restrict__ matches,
                         const float* __restrict__ R_gt, const float* __restrict__ t_gt,
                         const float* __restrict__ Kin,
                         const float* __restrict__ kp1,  const float* __restrict__ kp2,
                         float* __restrict__ ws)
{
    const int bid = blockIdx.x;
    const int b = bid >> 7;
    const int row0 = (bid & 127) * TN;
    const int t = threadIdx.x;
    const int lane = t & 63, wv = t >> 6;

    __shared__ float4 sTP[TN];
    __shared__ float  sm[4];
    __shared__ float4 paccL[4];
    __shared__ int    wtot[4];
    __shared__ unsigned int sOld;

    // issue all 8 matches loads first
    const float4* m4 = (const float4*)matches + ((long)b * N + row0) * (M/4) + t;
    float4 d[TN];
    #pragma unroll
    for (int n = 0; n < TN; ++n) d[n] = m4[n * (M/4)];

    // per-row broadcast: T = (R_gt @ homo(kp1))[:2] and kp1
    const float* Rgp = R_gt + b * 9;
    if (t < TN) {
        float2 p = ((const float2*)kp1)[(long)b * N + row0 + t];
        sTP[t] = make_float4(Rgp[0]*p.x + Rgp[1]*p.y + Rgp[2],
                             Rgp[3]*p.x + Rgp[4]*p.y + Rgp[5], p.x, p.y);
    }

    // F + per-column factors (overlaps load latency)
    float F[9];
    compute_F(Rgp, t_gt + b*3, Kin + b*9, F);
    const float4* kp2v = (const float4*)(kp2 + (long)b * M * 2);
    float4 q0 = kp2v[2*t], q1 = kp2v[2*t + 1];
    float k2x[4] = {q0.x, q0.z, q1.x, q1.z};
    float k2y[4] = {q0.y, q0.w, q1.y, q1.w};
    float A0[4], A1[4], A2[4];
    #pragma unroll
    for (int j = 0; j < 4; ++j) {
        A0[j] = k2x[j]*F[0] + k2y[j]*F[3] + F[6];
        A1[j] = k2x[j]*F[1] + k2y[j]*F[4] + F[7];
        A2[j] = k2x[j]*F[2] + k2y[j]*F[5] + F[8];
    }

    // wave max (needs d[] anyway)
    float v = NEG_INF;
    #pragma unroll
    for (int n = 0; n < TN; ++n)
        v = fmaxf(v, fmaxf(fmaxf(d[n].x, d[n].y), fmaxf(d[n].z, d[n].w)));
    #pragma unroll
    for (int off = 32; off; off >>= 1) v = fmaxf(v, __shfl_down(v, off));
    if (lane == 0) sm[wv] = v;
    __syncthreads();                       // sTP + sm ready

    float bmax = fmaxf(fmaxf(sm[0], sm[1]), fmaxf(sm[2], sm[3]));
    if (t == 0) ws[WS_PMAX + bid] = bmax;
    float thr_b = 0.1f * bmax;
    float cap_b = 1.01f * thr_b;

    // sums at local threshold + band count
    float s_w = 0.f, s_c = 0.f, s_e = 0.f, s_n = 0.f;
    int bcnt = 0;
    #pragma unroll
    for (int n = 0; n < TN; ++n) {
        float4 tp = sTP[n];
        float mv[4] = {d[n].x, d[n].y, d[n].z, d[n].w};
        #pragma unroll
        for (int j = 0; j < 4; ++j) {
            float w = mv[j];
            bool pass = w > thr_b;
            float ww = pass ? w : 0.f;
            s_n += pass ? 1.f : 0.f;
            bcnt += (pass && w <= cap_b) ? 1 : 0;
            float dx = k2x[j] - tp.x, dy = k2y[j] - tp.y;
            float ce = sqrtf(dx*dx + dy*dy);
            float ee = fabsf(A0[j]*tp.z + A1[j]*tp.w + A2[j]);
            s_w += ww; s_c += ce*ww; s_e += ee*ww;
        }
    }
    // wave-reduce sums + wave-scan band count
    #pragma unroll
    for (int off = 32; off; off >>= 1) {
        s_w += __shfl_down(s_w, off);
        s_c += __shfl_down(s_c, off);
        s_e += __shfl_down(s_e, off);
        s_n += __shfl_down(s_n, off);
    }
    int incl = bcnt;
    #pragma unroll
    for (int off = 1; off < 64; off <<= 1) {
        int y = __shfl_up(incl, off);
        if (lane >= off) incl += y;
    }
    if (lane == 0)  paccL[wv] = make_float4(s_w, s_c, s_e, s_n);
    if (lane == 63) wtot[wv] = incl;
    __syncthreads();

    int pos = incl - bcnt;
    #pragma unroll
    for (int k = 0; k < 4; ++k) if (k < wv) pos += wtot[k];
    int total = wtot[0] + wtot[1] + wtot[2] + wtot[3];

    if (t == 0) {
        float4 r = paccL[0];
        #pragma unroll
        for (int i = 1; i < 4; ++i) { r.x += paccL[i].x; r.y += paccL[i].y; r.z += paccL[i].z; r.w += paccL[i].w; }
        ((float4*)(ws + WS_PACC))[bid] = r;
        sOld = atomicAdd(((unsigned int*)ws) + WS_CNT + b * 16, (unsigned int)total);
    }
    __syncthreads();
    unsigned int old = sOld;

    if (total > 0 && old + (unsigned)total <= (unsigned)CAP) {
        float4* dense = (float4*)(ws + WS_DENSE) + (long)b * CAP + old;
        #pragma unroll
        for (int n = 0; n < TN; ++n) {
            float4 tp = sTP[n];
            float mv[4] = {d[n].x, d[n].y, d[n].z, d[n].w};
            #pragma unroll
            for (int j = 0; j < 4; ++j) {
                float w = mv[j];
                if (w > thr_b && w <= cap_b) {
                    float dx = k2x[j] - tp.x, dy = k2y[j] - tp.y;
                    float ce = sqrtf(dx*dx + dy*dy);
                    float ee = fabsf(A0[j]*tp.z + A1[j]*tp.w + A2[j]);
                    dense[pos++] = make_float4(w, ce * w, ee * w, 0.f);
                }
            }
        }
    }
}

// ---------- kernel 2: ONE block — thr, PACC sums, dense subtract, rare fallback, combine
__launch_bounds__(256)
__global__ void k2_final(const float* __restrict__ matches,
                         const float* __restrict__ R_pred, const float* __restrict__ t_pred,
                         const float* __restrict__ R_gt,   const float* __restrict__ t_gt,
                         const float* __restrict__ Kin,
                         const float* __restrict__ kp1,    const float* __restrict__ kp2,
                         float* __restrict__ ws, float* __restrict__ out)
{
    const int t = threadIdx.x;
    const int lane = t & 63;

    __shared__ float sThr[B];
    __shared__ int   sBad[B];
    __shared__ float sAcc[B][4];
    __shared__ float sPose[B];
    __shared__ float4 sTP[TN];

    // pose early (latency overlaps everything below)
    if (t < B) {
        sBad[t] = 0;
        const float* Rp = R_pred + t * 9;
        const float* Rq = R_gt   + t * 9;
        float trace = 0.f;
        #pragma unroll
        for (int i = 0; i < 9; ++i) trace += Rp[i] * Rq[i];
        float geo = fminf(fmaxf((trace - 1.f) * 0.5f, -1.f + 1e-7f), 1.f - 1e-7f);
        const float* tq = t_gt   + t * 3;
        const float* tp = t_pred + t * 3;
        float in2 = rsqrtf(tq[0]*tq[0] + tq[1]*tq[1] + tq[2]*tq[2]);
        float dotp = (tp[0]*tq[0] + tp[1]*tq[1] + tp[2]*tq[2]) * in2;
        sPose[t] = (1.f - geo) + (1.f - dotp);
    }

    // phase A: per-b threshold. thread t covers bids [8t, 8t+8) (all same b = t>>4)
    float pm[8];
    {
        int b = t >> 4;
        float v = NEG_INF;
        #pragma unroll
        for (int i = 0; i < 8; ++i) {
            pm[i] = ws[WS_PMAX + t*8 + i];
            v = fmaxf(v, pm[i]);
        }
        #pragma unroll
        for (int off = 8; off; off >>= 1) v = fmaxf(v, __shfl_down(v, off));
        if ((t & 15) == 0) sThr[b] = 0.1f * v;
    }
    __syncthreads();

    // flags: per-bid cap check + per-b overflow check
    {
        int b = t >> 4;
        float thr = sThr[b];
        #pragma unroll
        for (int i = 0; i < 8; ++i)
            if (thr > 1.01f * 0.1f * pm[i]) sBad[b] = 1;
        if (t < B) {
            unsigned int cnt = ((const unsigned int*)ws)[WS_CNT + t * 16];
            if (cnt > (unsigned)CAP) sBad[t] = 1;
        }
    }

    // phase B1: PACC sums -> sAcc[b]
    {
        int b = t >> 4, j = t & 15;
        const float4* pa = (const float4*)(ws + WS_PACC);
        float4 acc = make_float4(0.f, 0.f, 0.f, 0.f);
        #pragma unroll
        for (int k = 0; k < 8; ++k) {
            float4 r = pa[b*BPB + j + k*16];
            acc.x += r.x; acc.y += r.y; acc.z += r.z; acc.w += r.w;
        }
        #pragma unroll
        for (int off = 8; off; off >>= 1) {
            acc.x += __shfl_down(acc.x, off);
            acc.y += __shfl_down(acc.y, off);
            acc.z += __shfl_down(acc.z, off);
            acc.w += __shfl_down(acc.w, off);
        }
        if (j == 0) { sAcc[b][0] = acc.x; sAcc[b][1] = acc.y; sAcc[b][2] = acc.z; sAcc[b][3] = acc.w; }
    }
    __syncthreads();

    // phase B2: dense-list subtraction (coalesced, independent float4 loads)
    for (int b = 0; b < B; ++b) {
        if (sBad[b]) continue;
        float thr = sThr[b];
        unsigned int cnt = ((const unsigned int*)ws)[WS_CNT + b * 16];
        const float4* dense = (const float4*)(ws + WS_DENSE) + (long)b * CAP;
        float s0 = 0.f, s1 = 0.f, s2 = 0.f, s3 = 0.f;
        for (unsigned int i = t; i < cnt; i += 256) {
            float4 e = dense[i];
            if (!(e.x > thr)) { s0 += e.x; s1 += e.y; s2 += e.z; s3 += 1.f; }
        }
        #pragma unroll
        for (int off = 32; off; off >>= 1) {
            s0 += __shfl_down(s0, off);
            s1 += __shfl_down(s1, off);
            s2 += __shfl_down(s2, off);
            s3 += __shfl_down(s3, off);
        }
        if (lane == 0) {
            atomicAdd(&sAcc[b][0], -s0);
            atomicAdd(&sAcc[b][1], -s1);
            atomicAdd(&sAcc[b][2], -s2);
            atomicAdd(&sAcc[b][3], -s3);
        }
    }
    __syncthreads();

    // phase C: full per-b recompute fallback (normally never taken)
    for (int b = 0; b < B; ++b) {
        if (!sBad[b]) continue;
        __syncthreads();
        if (t < 4) sAcc[b][t] = 0.f;
        const float thr = sThr[b];
        const float* Rgp = R_gt + b * 9;
        float F[9];
        compute_F(Rgp, t_gt + b*3, Kin + b*9, F);
        const float4* kp2v = (const float4*)(kp2 + (long)b * M * 2);
        float4 q0 = kp2v[2*t], q1 = kp2v[2*t + 1];
        float k2x[4] = {q0.x, q0.z, q1.x, q1.z};
        float k2y[4] = {q0.y, q0.w, q1.y, q1.w};
        float A0[4], A1[4], A2[4];
        #pragma unroll
        for (int j = 0; j < 4; ++j) {
            A0[j] = k2x[j]*F[0] + k2y[j]*F[3] + F[6];
            A1[j] = k2x[j]*F[1] + k2y[j]*F[4] + F[7];
            A2[j] = k2x[j]*F[2] + k2y[j]*F[5] + F[8];
        }
        float s_w = 0.f, s_c = 0.f, s_e = 0.f, s_n = 0.f;
        for (int tile = 0; tile < BPB; ++tile) {
            int row0 = tile * TN;
            __syncthreads();
            if (t < TN) {
                float2 p = ((const float2*)kp1)[(long)b * N + row0 + t];
                sTP[t] = make_float4(Rgp[0]*p.x + Rgp[1]*p.y + Rgp[2],
                                     Rgp[3]*p.x + Rgp[4]*p.y + Rgp[5], p.x, p.y);
            }
            const float4* m4 = (const float4*)matches + ((long)b * N + row0) * (M/4) + t;
            float4 d[TN];
            #pragma unroll
            for (int n = 0; n < TN; ++n) d[n] = m4[n * (M/4)];
            __syncthreads();
            #pragma unroll
            for (int n = 0; n < TN; ++n) {
                float4 tp = sTP[n];
                float mv[4] = {d[n].x, d[n].y, d[n].z, d[n].w};
                #pragma unroll
                for (int j = 0; j < 4; ++j) {
                    float w = mv[j];
                    bool pass = w > thr;
                    float ww = pass ? w : 0.f;
                    s_n += pass ? 1.f : 0.f;
                    float dx = k2x[j] - tp.x, dy = k2y[j] - tp.y;
                    float ce = sqrtf(dx*dx + dy*dy);
                    float ee = fabsf(A0[j]*tp.z + A1[j]*tp.w + A2[j]);
                    s_w += ww; s_c += ce*ww; s_e += ee*ww;
                }
            }
        }
        #pragma unroll
        for (int off = 32; off; off >>= 1) {
            s_w += __shfl_down(s_w, off);
            s_c += __shfl_down(s_c, off);
            s_e += __shfl_down(s_e, off);
            s_n += __shfl_down(s_n, off);
        }
        if (lane == 0) {
            atomicAdd(&sAcc[b][0], s_w);
            atomicAdd(&sAcc[b][1], s_c);
            atomicAdd(&sAcc[b][2], s_e);
            atomicAdd(&sAcc[b][3], s_n);
        }
        __syncthreads();
    }
    __syncthreads();

    // phase D: combine
    if (t == 0) {
        float pose = 0.f, ms = 0.f, es = 0.f;
        int nv = 0;
        for (int bb = 0; bb < B; ++bb) {
            pose += sPose[bb];
            float sw = sAcc[bb][0], sc = sAcc[bb][1], se = sAcc[bb][2], cn = sAcc[bb][3];
            if (cn >= 3.f) { nv++; ms += sc / (sw + 1e-8f); es += se / (sw + 1e-8f); }
        }
        float match = nv > 0 ? ms / (float)nv : 0.f;
        float epi   = nv > 0 ? es / (float)nv : 0.f;
        out[0] = pose * (1.f / (float)B) + 0.5f * match + 0.1f * epi;
    }
}

extern "C" void kernel_launch(void* const* d_in, const int* in_sizes, int n_in,
                              void* d_out, int out_size, void* d_ws, size_t ws_size,
                              hipStream_t stream) {
    const float* R_pred  = (const float*)d_in[0];
    const float* t_pred  = (const float*)d_in[1];
    const float* R_gt    = (const float*)d_in[2];
    const float* t_gt    = (const float*)d_in[3];
    const float* K       = (const float*)d_in[4];
    const float* kp1     = (const float*)d_in[5];
    const float* kp2     = (const float*)d_in[6];
    const float* matches = (const float*)d_in[7];
    float* out = (float*)d_out;
    float* ws  = (float*)d_ws;

    // zero the 16 append counters (64B-strided, one cache line each)
    hipMemsetAsync(ws, 0, 1024, stream);
    k1_fused<<<NBLK, 256, 0, stream>>>(matches, R_gt, t_gt, K, kp1, kp2, ws);
    k2_final<<<1,    256, 0, stream>>>(matches, R_pred, t_pred, R_gt, t_gt, K, kp1, kp2, ws, out);
}

// Round 11
// 57.437 us; speedup vs baseline: 1.6911x; 1.3622x over previous
//
#include <hip/hip_runtime.h>

#define B 16
#define N 1024
#define M 1024
#define TN 8
#define BPB (N / TN)             // 128 blocks per batch entry
#define NBLK (B * BPB)           // 2048 blocks
#define CAP 4096                 // dense band capacity per batch entry

// ws float-index layout
#define WS_CNT   0               // per-b append counters (uint), stride 16 floats -> 0..255
#define WS_PMAX  256             // per-block max, NBLK -> 256..2303
#define WS_PACC  2304            // per-block {sum_w,sum_cw,sum_ew,count} float4, NBLK
#define WS_DENSE 10496           // per-b dense band lists, float4 entries, b*CAP

#define NEG_INF (-3.402823466e+38f)

// F row-major: F[i*3+l];  F = K^-T E K^-1, E = skew(t_n) R_gt
__device__ __forceinline__ void compute_F(const float* __restrict__ Rgp,
                                          const float* __restrict__ tg,
                                          const float* __restrict__ Km,
                                          float* F)
{
    float m00=Km[0], m01=Km[1], m02=Km[2];
    float m10=Km[3], m11=Km[4], m12=Km[5];
    float m20=Km[6], m21=Km[7], m22=Km[8];
    float c00 =  (m11*m22 - m12*m21), c01 = -(m10*m22 - m12*m20), c02 =  (m10*m21 - m11*m20);
    float c10 = -(m01*m22 - m02*m21), c11 =  (m00*m22 - m02*m20), c12 = -(m00*m21 - m01*m20);
    float c20 =  (m01*m12 - m02*m11), c21 = -(m00*m12 - m02*m10), c22 =  (m00*m11 - m01*m10);
    float id  = 1.f / (m00*c00 + m01*c01 + m02*c02);
    float Ki00 = c00*id, Ki01 = c10*id, Ki02 = c20*id;
    float Ki10 = c01*id, Ki11 = c11*id, Ki12 = c21*id;
    float Ki20 = c02*id, Ki21 = c12*id, Ki22 = c22*id;
    float inr = rsqrtf(tg[0]*tg[0] + tg[1]*tg[1] + tg[2]*tg[2]);
    float tx = tg[0]*inr, ty = tg[1]*inr, tz = tg[2]*inr;
    float Rg0=Rgp[0],Rg1=Rgp[1],Rg2=Rgp[2],Rg3=Rgp[3],Rg4=Rgp[4],Rg5=Rgp[5],Rg6=Rgp[6],Rg7=Rgp[7],Rg8=Rgp[8];
    float E00=-tz*Rg3+ty*Rg6, E01=-tz*Rg4+ty*Rg7, E02=-tz*Rg5+ty*Rg8;
    float E10= tz*Rg0-tx*Rg6, E11= tz*Rg1-tx*Rg7, E12= tz*Rg2-tx*Rg8;
    float E20=-ty*Rg0+tx*Rg3, E21=-ty*Rg1+tx*Rg4, E22=-ty*Rg2+tx*Rg5;
    float T00=E00*Ki00+E01*Ki10+E02*Ki20, T01=E00*Ki01+E01*Ki11+E02*Ki21, T02=E00*Ki02+E01*Ki12+E02*Ki22;
    float T10=E10*Ki00+E11*Ki10+E12*Ki20, T11=E10*Ki01+E11*Ki11+E12*Ki21, T12=E10*Ki02+E11*Ki12+E12*Ki22;
    float T20=E20*Ki00+E21*Ki10+E22*Ki20, T21=E20*Ki01+E21*Ki11+E22*Ki21, T22=E20*Ki02+E21*Ki12+E22*Ki22;
    F[0]=Ki00*T00+Ki10*T10+Ki20*T20; F[1]=Ki00*T01+Ki10*T11+Ki20*T21; F[2]=Ki00*T02+Ki10*T12+Ki20*T22;
    F[3]=Ki01*T00+Ki11*T10+Ki21*T20; F[4]=Ki01*T01+Ki11*T11+Ki21*T21; F[5]=Ki01*T02+Ki11*T12+Ki21*T22;
    F[6]=Ki02*T00+Ki12*T10+Ki22*T20; F[7]=Ki02*T01+Ki12*T11+Ki22*T21; F[8]=Ki02*T02+Ki12*T12+Ki22*T22;
}

// ---------- kernel 1: single full read of matches: max + local-thr sums + dense band append
__launch_bounds__(256, 4)
__global__ void k1_fused(const float* __restrict__ matches,
                         const float* __restrict__ R_gt, const float* __restrict__ t_gt,
                         const float* __restrict__ Kin,
                         const float* __restrict__ kp1,  const float* __restrict__ kp2,
                         float* __restrict__ ws)
{
    const int bid = blockIdx.x;
    const int b = bid >> 7;
    const int row0 = (bid & 127) * TN;
    const int t = threadIdx.x;
    const int lane = t & 63, wv = t >> 6;

    __shared__ float4 sTP[TN];
    __shared__ float  sm[4];
    __shared__ float4 paccL[4];
    __shared__ int    wtot[4];
    __shared__ unsigned int sOld;

    // issue all 8 matches loads first
    const float4* m4 = (const float4*)matches + ((long)b * N + row0) * (M/4) + t;
    float4 d[TN];
    #pragma unroll
    for (int n = 0; n < TN; ++n) d[n] = m4[n * (M/4)];

    // per-row broadcast: T = (R_gt @ homo(kp1))[:2] and kp1
    const float* Rgp = R_gt + b * 9;
    if (t < TN) {
        float2 p = ((const float2*)kp1)[(long)b * N + row0 + t];
        sTP[t] = make_float4(Rgp[0]*p.x + Rgp[1]*p.y + Rgp[2],
                             Rgp[3]*p.x + Rgp[4]*p.y + Rgp[5], p.x, p.y);
    }

    // F + per-column factors (overlaps load latency)
    float F[9];
    compute_F(Rgp, t_gt + b*3, Kin + b*9, F);
    const float4* kp2v = (const float4*)(kp2 + (long)b * M * 2);
    float4 q0 = kp2v[2*t], q1 = kp2v[2*t + 1];
    float k2x[4] = {q0.x, q0.z, q1.x, q1.z};
    float k2y[4] = {q0.y, q0.w, q1.y, q1.w};
    float A0[4], A1[4], A2[4];
    #pragma unroll
    for (int j = 0; j < 4; ++j) {
        A0[j] = k2x[j]*F[0] + k2y[j]*F[3] + F[6];
        A1[j] = k2x[j]*F[1] + k2y[j]*F[4] + F[7];
        A2[j] = k2x[j]*F[2] + k2y[j]*F[5] + F[8];
    }

    // wave max
    float v = NEG_INF;
    #pragma unroll
    for (int n = 0; n < TN; ++n)
        v = fmaxf(v, fmaxf(fmaxf(d[n].x, d[n].y), fmaxf(d[n].z, d[n].w)));
    #pragma unroll
    for (int off = 32; off; off >>= 1) v = fmaxf(v, __shfl_down(v, off));
    if (lane == 0) sm[wv] = v;
    __syncthreads();                       // sTP + sm ready

    float bmax = fmaxf(fmaxf(sm[0], sm[1]), fmaxf(sm[2], sm[3]));
    if (t == 0) ws[WS_PMAX + bid] = bmax;
    float thr_b = 0.1f * bmax;
    float cap_b = 1.01f * thr_b;

    // sums at local threshold + band count
    float s_w = 0.f, s_c = 0.f, s_e = 0.f, s_n = 0.f;
    int bcnt = 0;
    #pragma unroll
    for (int n = 0; n < TN; ++n) {
        float4 tp = sTP[n];
        float mv[4] = {d[n].x, d[n].y, d[n].z, d[n].w};
        #pragma unroll
        for (int j = 0; j < 4; ++j) {
            float w = mv[j];
            bool pass = w > thr_b;
            float ww = pass ? w : 0.f;
            s_n += pass ? 1.f : 0.f;
            bcnt += (pass && w <= cap_b) ? 1 : 0;
            float dx = k2x[j] - tp.x, dy = k2y[j] - tp.y;
            float ce = sqrtf(dx*dx + dy*dy);
            float ee = fabsf(A0[j]*tp.z + A1[j]*tp.w + A2[j]);
            s_w += ww; s_c += ce*ww; s_e += ee*ww;
        }
    }
    // wave-reduce sums + wave-scan band count
    #pragma unroll
    for (int off = 32; off; off >>= 1) {
        s_w += __shfl_down(s_w, off);
        s_c += __shfl_down(s_c, off);
        s_e += __shfl_down(s_e, off);
        s_n += __shfl_down(s_n, off);
    }
    int incl = bcnt;
    #pragma unroll
    for (int off = 1; off < 64; off <<= 1) {
        int y = __shfl_up(incl, off);
        if (lane >= off) incl += y;
    }
    if (lane == 0)  paccL[wv] = make_float4(s_w, s_c, s_e, s_n);
    if (lane == 63) wtot[wv] = incl;
    __syncthreads();

    int pos = incl - bcnt;
    #pragma unroll
    for (int k = 0; k < 4; ++k) if (k < wv) pos += wtot[k];
    int total = wtot[0] + wtot[1] + wtot[2] + wtot[3];

    if (t == 0) {
        float4 r = paccL[0];
        #pragma unroll
        for (int i = 1; i < 4; ++i) { r.x += paccL[i].x; r.y += paccL[i].y; r.z += paccL[i].z; r.w += paccL[i].w; }
        ((float4*)(ws + WS_PACC))[bid] = r;
        sOld = atomicAdd(((unsigned int*)ws) + WS_CNT + b * 16, (unsigned int)total);
    }
    __syncthreads();
    unsigned int old = sOld;

    if (total > 0 && old + (unsigned)total <= (unsigned)CAP) {
        float4* dense = (float4*)(ws + WS_DENSE) + (long)b * CAP + old;
        #pragma unroll
        for (int n = 0; n < TN; ++n) {
            float4 tp = sTP[n];
            float mv[4] = {d[n].x, d[n].y, d[n].z, d[n].w};
            #pragma unroll
            for (int j = 0; j < 4; ++j) {
                float w = mv[j];
                if (w > thr_b && w <= cap_b) {
                    float dx = k2x[j] - tp.x, dy = k2y[j] - tp.y;
                    float ce = sqrtf(dx*dx + dy*dy);
                    float ee = fabsf(A0[j]*tp.z + A1[j]*tp.w + A2[j]);
                    dense[pos++] = make_float4(w, ce * w, ee * w, 0.f);
                }
            }
        }
    }
}

// ---------- kernel 2: ONE block — all 16 b's processed CONCURRENTLY (wave-per-b)
__launch_bounds__(256)
__global__ void k2_final(const float* __restrict__ matches,
                         const float* __restrict__ R_pred, const float* __restrict__ t_pred,
                         const float* __restrict__ R_gt,   const float* __restrict__ t_gt,
                         const float* __restrict__ Kin,
                         const float* __restrict__ kp1,    const float* __restrict__ kp2,
                         float* __restrict__ ws, float* __restrict__ out)
{
    const int t = threadIdx.x;
    const int lane = t & 63, wv = t >> 6;

    __shared__ float sThr[B];
    __shared__ int   sBad[B];
    __shared__ unsigned int sCnt[B];
    __shared__ float sAcc[B][4];
    __shared__ float sPose[B];
    __shared__ float4 sTP[TN];

    // preload cnt + pose early (latency overlaps phase A)
    if (t < B) {
        sBad[t] = 0;
        sCnt[t] = ((const unsigned int*)ws)[WS_CNT + t * 16];
        const float* Rp = R_pred + t * 9;
        const float* Rq = R_gt   + t * 9;
        float trace = 0.f;
        #pragma unroll
        for (int i = 0; i < 9; ++i) trace += Rp[i] * Rq[i];
        float geo = fminf(fmaxf((trace - 1.f) * 0.5f, -1.f + 1e-7f), 1.f - 1e-7f);
        const float* tq = t_gt   + t * 3;
        const float* tp = t_pred + t * 3;
        float in2 = rsqrtf(tq[0]*tq[0] + tq[1]*tq[1] + tq[2]*tq[2]);
        float dotp = (tp[0]*tq[0] + tp[1]*tq[1] + tp[2]*tq[2]) * in2;
        sPose[t] = (1.f - geo) + (1.f - dotp);
    }

    // phase A: per-b threshold. thread t covers PMAX[8t..8t+8) (all same b = t>>4)
    float pm[8];
    {
        int b = t >> 4;
        float v = NEG_INF;
        #pragma unroll
        for (int i = 0; i < 8; ++i) {
            pm[i] = ws[WS_PMAX + t*8 + i];
            v = fmaxf(v, pm[i]);
        }
        #pragma unroll
        for (int off = 8; off; off >>= 1) v = fmaxf(v, __shfl_down(v, off));
        if ((t & 15) == 0) sThr[b] = 0.1f * v;
    }
    __syncthreads();

    // flags: per-bid cap check (bit-identical expression order to k1) + per-b overflow
    {
        int b = t >> 4;
        float thr = sThr[b];
        #pragma unroll
        for (int i = 0; i < 8; ++i) {
            float cap_i = 1.01f * (0.1f * pm[i]);   // == k1's 1.01f * thr_b
            if (thr > cap_i) sBad[b] = 1;
        }
        if (t < B && sCnt[t] > (unsigned)CAP) sBad[t] = 1;
    }

    // phase B1: PACC sums -> sAcc[b]
    {
        int b = t >> 4, j = t & 15;
        const float4* pa = (const float4*)(ws + WS_PACC);
        float4 acc = make_float4(0.f, 0.f, 0.f, 0.f);
        #pragma unroll
        for (int k = 0; k < 8; ++k) {
            float4 r = pa[b*BPB + j + k*16];
            acc.x += r.x; acc.y += r.y; acc.z += r.z; acc.w += r.w;
        }
        #pragma unroll
        for (int off = 8; off; off >>= 1) {
            acc.x += __shfl_down(acc.x, off);
            acc.y += __shfl_down(acc.y, off);
            acc.z += __shfl_down(acc.z, off);
            acc.w += __shfl_down(acc.w, off);
        }
        if (j == 0) { sAcc[b][0] = acc.x; sAcc[b][1] = acc.y; sAcc[b][2] = acc.z; sAcc[b][3] = acc.w; }
    }
    __syncthreads();

    // phase B2: wave wv handles b = wv + 4*rb — 4 waves x 4 b's, all concurrent,
    // 4-way unrolled predicated loads (4 independent misses in flight)
    for (int rb = 0; rb < 4; ++rb) {
        int b = wv + rb * 4;
        if (sBad[b]) continue;
        float thr = sThr[b];
        unsigned int cnt = sCnt[b];
        const float4* dense = (const float4*)(ws + WS_DENSE) + (long)b * CAP;
        float s0 = 0.f, s1 = 0.f, s2 = 0.f, s3 = 0.f;
        for (unsigned int base = 0; base < cnt; base += 256) {
            unsigned int i0 = base + lane;
            unsigned int i1 = i0 + 64, i2 = i0 + 128, i3 = i0 + 192;
            float4 z = make_float4(2.f, 0.f, 0.f, 0.f);   // w=2 > thr always -> ignored
            float4 e0 = (i0 < cnt) ? dense[i0] : z;
            float4 e1 = (i1 < cnt) ? dense[i1] : z;
            float4 e2 = (i2 < cnt) ? dense[i2] : z;
            float4 e3 = (i3 < cnt) ? dense[i3] : z;
            if (!(e0.x > thr)) { s0 += e0.x; s1 += e0.y; s2 += e0.z; s3 += 1.f; }
            if (!(e1.x > thr)) { s0 += e1.x; s1 += e1.y; s2 += e1.z; s3 += 1.f; }
            if (!(e2.x > thr)) { s0 += e2.x; s1 += e2.y; s2 += e2.z; s3 += 1.f; }
            if (!(e3.x > thr)) { s0 += e3.x; s1 += e3.y; s2 += e3.z; s3 += 1.f; }
        }
        #pragma unroll
        for (int off = 32; off; off >>= 1) {
            s0 += __shfl_down(s0, off);
            s1 += __shfl_down(s1, off);
            s2 += __shfl_down(s2, off);
            s3 += __shfl_down(s3, off);
        }
        if (lane == 0) {    // single writer wave per b — no atomics
            sAcc[b][0] -= s0; sAcc[b][1] -= s1; sAcc[b][2] -= s2; sAcc[b][3] -= s3;
        }
    }
    __syncthreads();

    // phase C: full per-b recompute fallback (normally never taken)
    for (int b = 0; b < B; ++b) {
        if (!sBad[b]) continue;
        __syncthreads();
        if (t < 4) sAcc[b][t] = 0.f;
        const float thr = sThr[b];
        const float* Rgp = R_gt + b * 9;
        float F[9];
        compute_F(Rgp, t_gt + b*3, Kin + b*9, F);
        const float4* kp2v = (const float4*)(kp2 + (long)b * M * 2);
        float4 q0 = kp2v[2*t], q1 = kp2v[2*t + 1];
        float k2x[4] = {q0.x, q0.z, q1.x, q1.z};
        float k2y[4] = {q0.y, q0.w, q1.y, q1.w};
        float A0[4], A1[4], A2[4];
        #pragma unroll
        for (int j = 0; j < 4; ++j) {
            A0[j] = k2x[j]*F[0] + k2y[j]*F[3] + F[6];
            A1[j] = k2x[j]*F[1] + k2y[j]*F[4] + F[7];
            A2[j] = k2x[j]*F[2] + k2y[j]*F[5] + F[8];
        }
        float s_w = 0.f, s_c = 0.f, s_e = 0.f, s_n = 0.f;
        for (int tile = 0; tile < BPB; ++tile) {
            int row0 = tile * TN;
            __syncthreads();
            if (t < TN) {
                float2 p = ((const float2*)kp1)[(long)b * N + row0 + t];
                sTP[t] = make_float4(Rgp[0]*p.x + Rgp[1]*p.y + Rgp[2],
                                     Rgp[3]*p.x + Rgp[4]*p.y + Rgp[5], p.x, p.y);
            }
            const float4* m4 = (const float4*)matches + ((long)b * N + row0) * (M/4) + t;
            float4 d[TN];
            #pragma unroll
            for (int n = 0; n < TN; ++n) d[n] = m4[n * (M/4)];
            __syncthreads();
            #pragma unroll
            for (int n = 0; n < TN; ++n) {
                float4 tp = sTP[n];
                float mv[4] = {d[n].x, d[n].y, d[n].z, d[n].w};
                #pragma unroll
                for (int j = 0; j < 4; ++j) {
                    float w = mv[j];
                    bool pass = w > thr;
                    float ww = pass ? w : 0.f;
                    s_n += pass ? 1.f : 0.f;
                    float dx = k2x[j] - tp.x, dy = k2y[j] - tp.y;
                    float ce = sqrtf(dx*dx + dy*dy);
                    float ee = fabsf(A0[j]*tp.z + A1[j]*tp.w + A2[j]);
                    s_w += ww; s_c += ce*ww; s_e += ee*ww;
                }
            }
        }
        #pragma unroll
        for (int off = 32; off; off >>= 1) {
            s_w += __shfl_down(s_w, off);
            s_c += __shfl_down(s_c, off);
            s_e += __shfl_down(s_e, off);
            s_n += __shfl_down(s_n, off);
        }
        if (lane == 0) {
            atomicAdd(&sAcc[b][0], s_w);
            atomicAdd(&sAcc[b][1], s_c);
            atomicAdd(&sAcc[b][2], s_e);
            atomicAdd(&sAcc[b][3], s_n);
        }
        __syncthreads();
    }
    __syncthreads();

    // phase D: combine
    if (t == 0) {
        float pose = 0.f, ms = 0.f, es = 0.f;
        int nv = 0;
        for (int bb = 0; bb < B; ++bb) {
            pose += sPose[bb];
            float sw = sAcc[bb][0], sc = sAcc[bb][1], se = sAcc[bb][2], cn = sAcc[bb][3];
            if (cn >= 3.f) { nv++; ms += sc / (sw + 1e-8f); es += se / (sw + 1e-8f); }
        }
        float match = nv > 0 ? ms / (float)nv : 0.f;
        float epi   = nv > 0 ? es / (float)nv : 0.f;
        out[0] = pose * (1.f / (float)B) + 0.5f * match + 0.1f * epi;
    }
}

extern "C" void kernel_launch(void* const* d_in, const int* in_sizes, int n_in,
                              void* d_out, int out_size, void* d_ws, size_t ws_size,
                              hipStream_t stream) {
    const float* R_pred  = (const float*)d_in[0];
    const float* t_pred  = (const float*)d_in[1];
    const float* R_gt    = (const float*)d_in[2];
    const float* t_gt    = (const float*)d_in[3];
    const float* K       = (const float*)d_in[4];
    const float* kp1     = (const float*)d_in[5];
    const float* kp2     = (const float*)d_in[6];
    const float* matches = (const float*)d_in[7];
    float* out = (float*)d_out;
    float* ws  = (float*)d_ws;

    // zero the 16 append counters (64B-strided, one cache line each)
    hipMemsetAsync(ws, 0, 1024, stream);
    k1_fused<<<NBLK, 256, 0, stream>>>(matches, R_gt, t_gt, K, kp1, kp2, ws);
    k2_final<<<1,    256, 0, stream>>>(matches, R_pred, t_pred, R_gt, t_gt, K, kp1, kp2, ws, out);
}

// Round 12
// 51.247 us; speedup vs baseline: 1.8954x; 1.1208x over previous
//
#include <hip/hip_runtime.h>

#define B 16
#define N 1024
#define M 1024
#define TN 8
#define BPB (N / TN)             // 128 blocks per batch entry
#define NBLK (B * BPB)           // 2048 blocks
#define C2 64                    // band capacity per block (slots)

// ws float-index layout
#define WS_CNTR  0               // final counter (uint)
#define WS_RES   16              // per-b {sw, sc, se, cn, pose}, stride 8 -> 16..143
#define WS_PMAX  256             // per-block max, NBLK -> 256..2303
#define WS_BCNT  2304            // per-block band count (uint), NBLK -> 2304..4351
#define WS_PACC  4352            // per-block {sum_w,sum_cw,sum_ew,count} float4, NBLK
#define WS_BAND  12544           // per-block band float4 {w, w*ce, w*ee, 0}, NBLK*C2

#define NEG_INF (-3.402823466e+38f)

// F row-major: F[i*3+l];  F = K^-T E K^-1, E = skew(t_n) R_gt
__device__ __forceinline__ void compute_F(const float* __restrict__ Rgp,
                                          const float* __restrict__ tg,
                                          const float* __restrict__ Km,
                                          float* F)
{
    float m00=Km[0], m01=Km[1], m02=Km[2];
    float m10=Km[3], m11=Km[4], m12=Km[5];
    float m20=Km[6], m21=Km[7], m22=Km[8];
    float c00 =  (m11*m22 - m12*m21), c01 = -(m10*m22 - m12*m20), c02 =  (m10*m21 - m11*m20);
    float c10 = -(m01*m22 - m02*m21), c11 =  (m00*m22 - m02*m20), c12 = -(m00*m21 - m01*m20);
    float c20 =  (m01*m12 - m02*m11), c21 = -(m00*m12 - m02*m10), c22 =  (m00*m11 - m01*m10);
    float id  = 1.f / (m00*c00 + m01*c01 + m02*c02);
    float Ki00 = c00*id, Ki01 = c10*id, Ki02 = c20*id;
    float Ki10 = c01*id, Ki11 = c11*id, Ki12 = c21*id;
    float Ki20 = c02*id, Ki21 = c12*id, Ki22 = c22*id;
    float inr = rsqrtf(tg[0]*tg[0] + tg[1]*tg[1] + tg[2]*tg[2]);
    float tx = tg[0]*inr, ty = tg[1]*inr, tz = tg[2]*inr;
    float Rg0=Rgp[0],Rg1=Rgp[1],Rg2=Rgp[2],Rg3=Rgp[3],Rg4=Rgp[4],Rg5=Rgp[5],Rg6=Rgp[6],Rg7=Rgp[7],Rg8=Rgp[8];
    float E00=-tz*Rg3+ty*Rg6, E01=-tz*Rg4+ty*Rg7, E02=-tz*Rg5+ty*Rg8;
    float E10= tz*Rg0-tx*Rg6, E11= tz*Rg1-tx*Rg7, E12= tz*Rg2-tx*Rg8;
    float E20=-ty*Rg0+tx*Rg3, E21=-ty*Rg1+tx*Rg4, E22=-ty*Rg2+tx*Rg5;
    float T00=E00*Ki00+E01*Ki10+E02*Ki20, T01=E00*Ki01+E01*Ki11+E02*Ki21, T02=E00*Ki02+E01*Ki12+E02*Ki22;
    float T10=E10*Ki00+E11*Ki10+E12*Ki20, T11=E10*Ki01+E11*Ki11+E12*Ki21, T12=E10*Ki02+E11*Ki12+E12*Ki22;
    float T20=E20*Ki00+E21*Ki10+E22*Ki20, T21=E20*Ki01+E21*Ki11+E22*Ki21, T22=E20*Ki02+E21*Ki12+E22*Ki22;
    F[0]=Ki00*T00+Ki10*T10+Ki20*T20; F[1]=Ki00*T01+Ki10*T11+Ki20*T21; F[2]=Ki00*T02+Ki10*T12+Ki20*T22;
    F[3]=Ki01*T00+Ki11*T10+Ki21*T20; F[4]=Ki01*T01+Ki11*T11+Ki21*T21; F[5]=Ki01*T02+Ki11*T12+Ki21*T22;
    F[6]=Ki02*T00+Ki12*T10+Ki22*T20; F[7]=Ki02*T01+Ki12*T11+Ki22*T21; F[8]=Ki02*T02+Ki12*T12+Ki22*T22;
}

// ---------- kernel 1: single full read of matches: max + local-thr sums + per-block band
//            (NO global atomics, NO fences — pure overwrites at fixed offsets)
__launch_bounds__(256, 4)
__global__ void k1_fused(const float* __restrict__ matches,
                         const float* __restrict__ R_gt, const float* __restrict__ t_gt,
                         const float* __restrict__ Kin,
                         const float* __restrict__ kp1,  const float* __restrict__ kp2,
                         float* __restrict__ ws)
{
    const int bid = blockIdx.x;
    const int b = bid >> 7;
    const int row0 = (bid & 127) * TN;
    const int t = threadIdx.x;
    const int lane = t & 63, wv = t >> 6;
    if (bid == 0 && t == 0) ((unsigned int*)ws)[WS_CNTR] = 0u;

    __shared__ float4 sTP[TN];
    __shared__ float  sm[4];
    __shared__ float4 paccL[4];
    __shared__ int    wtot[4];

    // issue all 8 matches loads first (32 VGPRs in flight)
    const float4* m4 = (const float4*)matches + ((long)b * N + row0) * (M/4) + t;
    float4 d[TN];
    #pragma unroll
    for (int n = 0; n < TN; ++n) d[n] = m4[n * (M/4)];

    // per-row broadcast: T = (R_gt @ homo(kp1))[:2] and kp1
    const float* Rgp = R_gt + b * 9;
    if (t < TN) {
        float2 p = ((const float2*)kp1)[(long)b * N + row0 + t];
        sTP[t] = make_float4(Rgp[0]*p.x + Rgp[1]*p.y + Rgp[2],
                             Rgp[3]*p.x + Rgp[4]*p.y + Rgp[5], p.x, p.y);
    }

    // F + per-column factors (overlaps load latency)
    float F[9];
    compute_F(Rgp, t_gt + b*3, Kin + b*9, F);
    const float4* kp2v = (const float4*)(kp2 + (long)b * M * 2);
    float4 q0 = kp2v[2*t], q1 = kp2v[2*t + 1];
    float k2x[4] = {q0.x, q0.z, q1.x, q1.z};
    float k2y[4] = {q0.y, q0.w, q1.y, q1.w};
    float A0[4], A1[4], A2[4];
    #pragma unroll
    for (int j = 0; j < 4; ++j) {
        A0[j] = k2x[j]*F[0] + k2y[j]*F[3] + F[6];
        A1[j] = k2x[j]*F[1] + k2y[j]*F[4] + F[7];
        A2[j] = k2x[j]*F[2] + k2y[j]*F[5] + F[8];
    }

    // wave max
    float v = NEG_INF;
    #pragma unroll
    for (int n = 0; n < TN; ++n)
        v = fmaxf(v, fmaxf(fmaxf(d[n].x, d[n].y), fmaxf(d[n].z, d[n].w)));
    #pragma unroll
    for (int off = 32; off; off >>= 1) v = fmaxf(v, __shfl_down(v, off));
    if (lane == 0) sm[wv] = v;
    __syncthreads();                       // sTP + sm ready

    float bmax = fmaxf(fmaxf(sm[0], sm[1]), fmaxf(sm[2], sm[3]));
    if (t == 0) ws[WS_PMAX + bid] = bmax;
    float thr_b = 0.1f * bmax;
    float cap_b = 1.01f * thr_b;

    // sums at local threshold + band count
    float s_w = 0.f, s_c = 0.f, s_e = 0.f, s_n = 0.f;
    int bcnt = 0;
    #pragma unroll
    for (int n = 0; n < TN; ++n) {
        float4 tp = sTP[n];
        float mv[4] = {d[n].x, d[n].y, d[n].z, d[n].w};
        #pragma unroll
        for (int j = 0; j < 4; ++j) {
            float w = mv[j];
            bool pass = w > thr_b;
            float ww = pass ? w : 0.f;
            s_n += pass ? 1.f : 0.f;
            bcnt += (pass && w <= cap_b) ? 1 : 0;
            float dx = k2x[j] - tp.x, dy = k2y[j] - tp.y;
            float ce = sqrtf(dx*dx + dy*dy);
            float ee = fabsf(A0[j]*tp.z + A1[j]*tp.w + A2[j]);
            s_w += ww; s_c += ce*ww; s_e += ee*ww;
        }
    }
    // wave-reduce sums + wave-scan band count
    #pragma unroll
    for (int off = 32; off; off >>= 1) {
        s_w += __shfl_down(s_w, off);
        s_c += __shfl_down(s_c, off);
        s_e += __shfl_down(s_e, off);
        s_n += __shfl_down(s_n, off);
    }
    int incl = bcnt;
    #pragma unroll
    for (int off = 1; off < 64; off <<= 1) {
        int y = __shfl_up(incl, off);
        if (lane >= off) incl += y;
    }
    if (lane == 0)  paccL[wv] = make_float4(s_w, s_c, s_e, s_n);
    if (lane == 63) wtot[wv] = incl;
    __syncthreads();
    if (t == 0) {
        float4 r = paccL[0];
        #pragma unroll
        for (int i = 1; i < 4; ++i) { r.x += paccL[i].x; r.y += paccL[i].y; r.z += paccL[i].z; r.w += paccL[i].w; }
        ((float4*)(ws + WS_PACC))[bid] = r;
    }
    int pos = incl - bcnt;
    #pragma unroll
    for (int k = 0; k < 4; ++k) if (k < wv) pos += wtot[k];
    int total = wtot[0] + wtot[1] + wtot[2] + wtot[3];
    if (t == 0) ((unsigned int*)ws)[WS_BCNT + bid] = (unsigned int)total;

    if (total > 0 && total <= C2) {
        float4* bandv = (float4*)(ws + WS_BAND) + (long)bid * C2;
        #pragma unroll
        for (int n = 0; n < TN; ++n) {
            float4 tp = sTP[n];
            float mv[4] = {d[n].x, d[n].y, d[n].z, d[n].w};
            #pragma unroll
            for (int j = 0; j < 4; ++j) {
                float w = mv[j];
                if (w > thr_b && w <= cap_b) {
                    float dx = k2x[j] - tp.x, dy = k2y[j] - tp.y;
                    float ce = sqrtf(dx*dx + dy*dy);
                    float ee = fabsf(A0[j]*tp.z + A1[j]*tp.w + A2[j]);
                    bandv[pos++] = make_float4(w, ce * w, ee * w, 0.f);
                }
            }
        }
    }
}

// ---------- kernel 2: 16 blocks (one per b) — LDS-cached metadata, FLAT-SLOT band walk
//            (all loads independent+coalesced), rare fallback, per-b result, last combines.
__launch_bounds__(256)
__global__ void k2_perb(const float* __restrict__ matches,
                        const float* __restrict__ R_pred, const float* __restrict__ t_pred,
                        const float* __restrict__ R_gt,   const float* __restrict__ t_gt,
                        const float* __restrict__ Kin,
                        const float* __restrict__ kp1,    const float* __restrict__ kp2,
                        float* __restrict__ ws, float* __restrict__ out)
{
    const int b = blockIdx.x;
    const int t = threadIdx.x;
    const int lane = t & 63, wv = t >> 6;

    __shared__ float        sPM[BPB];
    __shared__ unsigned int sBC[BPB];
    __shared__ int          sBad[BPB];
    __shared__ float        sThr;
    __shared__ float4       sPacc[2];
    __shared__ float        sAcc4[4];
    __shared__ int          sFlag[BPB];
    __shared__ int          sNFlag;
    __shared__ int          sLast;
    __shared__ float4       sTP[TN];

    if (t == 0) sNFlag = 0;

    // coalesced metadata preload (PMAX, BCNT, PACC) — independent loads, one round
    float4 myPacc = make_float4(0.f, 0.f, 0.f, 0.f);
    if (t < BPB) {
        sPM[t] = ws[WS_PMAX + b*BPB + t];
        sBC[t] = ((const unsigned int*)ws)[WS_BCNT + b*BPB + t];
        myPacc = ((const float4*)(ws + WS_PACC))[b*BPB + t];
    }
    __syncthreads();

    // true threshold
    if (t < 64) {
        float v = fmaxf(sPM[t], sPM[t + 64]);
        #pragma unroll
        for (int off = 32; off; off >>= 1) v = fmaxf(v, __shfl_down(v, off));
        if (t == 0) sThr = 0.1f * v;
    }
    __syncthreads();
    const float thr = sThr;

    // bad flags; zero bad bids' PACC contribution (phase C re-adds their full sums)
    if (t < BPB) {
        bool bad = (sBC[t] > (unsigned)C2) || (thr > 1.01f * (0.1f * sPM[t]));
        sBad[t] = bad ? 1 : 0;
        if (bad) {
            int i = atomicAdd(&sNFlag, 1);
            sFlag[i] = t;
            myPacc = make_float4(0.f, 0.f, 0.f, 0.f);
        }
    }
    // PACC reduce (waves 0 and 1 hold the 128 values)
    #pragma unroll
    for (int off = 32; off; off >>= 1) {
        myPacc.x += __shfl_down(myPacc.x, off);
        myPacc.y += __shfl_down(myPacc.y, off);
        myPacc.z += __shfl_down(myPacc.z, off);
        myPacc.w += __shfl_down(myPacc.w, off);
    }
    if (t < BPB && lane == 0) sPacc[wv] = myPacc;
    __syncthreads();
    if (t == 0) {
        sAcc4[0] = sPacc[0].x + sPacc[1].x;
        sAcc4[1] = sPacc[0].y + sPacc[1].y;
        sAcc4[2] = sPacc[0].z + sPacc[1].z;
        sAcc4[3] = sPacc[0].w + sPacc[1].w;
    }
    __syncthreads();

    // flat-slot band walk: slot s -> bid (s>>6), slot k (s&63); loads independent & coalesced
    {
        float s0 = 0.f, s1 = 0.f, s2 = 0.f, s3 = 0.f;
        const float4* bandv = (const float4*)(ws + WS_BAND) + (long)b * BPB * C2;
        for (int s = t; s < BPB * C2; s += 256) {
            int bidl = s >> 6, k = s & 63;
            if (!sBad[bidl] && (unsigned)k < sBC[bidl]) {
                float4 e = bandv[bidl * C2 + k];
                if (!(e.x > thr)) { s0 += e.x; s1 += e.y; s2 += e.z; s3 += 1.f; }
            }
        }
        #pragma unroll
        for (int off = 32; off; off >>= 1) {
            s0 += __shfl_down(s0, off);
            s1 += __shfl_down(s1, off);
            s2 += __shfl_down(s2, off);
            s3 += __shfl_down(s3, off);
        }
        if (lane == 0) {
            atomicAdd(&sAcc4[0], -s0);
            atomicAdd(&sAcc4[1], -s1);
            atomicAdd(&sAcc4[2], -s2);
            atomicAdd(&sAcc4[3], -s3);
        }
    }
    __syncthreads();

    // fallback: full recompute of flagged tiles with true thr (normally 0)
    const int nflag = sNFlag;
    for (int f = 0; f < nflag; ++f) {
        __syncthreads();
        int rrow0 = sFlag[f] * TN;
        const float* Rgp = R_gt + b * 9;
        if (t < TN) {
            float2 p = ((const float2*)kp1)[(long)b * N + rrow0 + t];
            sTP[t] = make_float4(Rgp[0]*p.x + Rgp[1]*p.y + Rgp[2],
                                 Rgp[3]*p.x + Rgp[4]*p.y + Rgp[5], p.x, p.y);
        }
        float F[9];
        compute_F(Rgp, t_gt + b*3, Kin + b*9, F);
        const float4* kp2v = (const float4*)(kp2 + (long)b * M * 2);
        float4 q0 = kp2v[2*t], q1 = kp2v[2*t + 1];
        float k2x[4] = {q0.x, q0.z, q1.x, q1.z};
        float k2y[4] = {q0.y, q0.w, q1.y, q1.w};
        float A0[4], A1[4], A2[4];
        #pragma unroll
        for (int j = 0; j < 4; ++j) {
            A0[j] = k2x[j]*F[0] + k2y[j]*F[3] + F[6];
            A1[j] = k2x[j]*F[1] + k2y[j]*F[4] + F[7];
            A2[j] = k2x[j]*F[2] + k2y[j]*F[5] + F[8];
        }
        const float4* m4 = (const float4*)matches + ((long)b * N + rrow0) * (M/4) + t;
        float4 d[TN];
        #pragma unroll
        for (int n = 0; n < TN; ++n) d[n] = m4[n * (M/4)];
        __syncthreads();
        float s_w = 0.f, s_c = 0.f, s_e = 0.f, s_n = 0.f;
        #pragma unroll
        for (int n = 0; n < TN; ++n) {
            float4 tp = sTP[n];
            float mv[4] = {d[n].x, d[n].y, d[n].z, d[n].w};
            #pragma unroll
            for (int j = 0; j < 4; ++j) {
                float w = mv[j];
                bool pass = w > thr;
                float ww = pass ? w : 0.f;
                s_n += pass ? 1.f : 0.f;
                float dx = k2x[j] - tp.x, dy = k2y[j] - tp.y;
                float ce = sqrtf(dx*dx + dy*dy);
                float ee = fabsf(A0[j]*tp.z + A1[j]*tp.w + A2[j]);
                s_w += ww; s_c += ce*ww; s_e += ee*ww;
            }
        }
        #pragma unroll
        for (int off = 32; off; off >>= 1) {
            s_w += __shfl_down(s_w, off);
            s_c += __shfl_down(s_c, off);
            s_e += __shfl_down(s_e, off);
            s_n += __shfl_down(s_n, off);
        }
        if (lane == 0) {
            atomicAdd(&sAcc4[0], s_w);
            atomicAdd(&sAcc4[1], s_c);
            atomicAdd(&sAcc4[2], s_e);
            atomicAdd(&sAcc4[3], s_n);
        }
        __syncthreads();
    }
    __syncthreads();

    // per-b pose + result; last of the 16 blocks combines (16 fences/atomics — cheap)
    if (t == 0) {
        const float* Rp = R_pred + b * 9;
        const float* Rq = R_gt   + b * 9;
        float trace = 0.f;
        #pragma unroll
        for (int i = 0; i < 9; ++i) trace += Rp[i] * Rq[i];
        float geo = fminf(fmaxf((trace - 1.f) * 0.5f, -1.f + 1e-7f), 1.f - 1e-7f);
        const float* tq = t_gt   + b * 3;
        const float* tp = t_pred + b * 3;
        float in2 = rsqrtf(tq[0]*tq[0] + tq[1]*tq[1] + tq[2]*tq[2]);
        float dotp = (tp[0]*tq[0] + tp[1]*tq[1] + tp[2]*tq[2]) * in2;
        float* res = ws + WS_RES + b * 8;
        res[0] = sAcc4[0]; res[1] = sAcc4[1]; res[2] = sAcc4[2]; res[3] = sAcc4[3];
        res[4] = (1.f - geo) + (1.f - dotp);
        __threadfence();
        unsigned int old = atomicAdd(((unsigned int*)ws) + WS_CNTR, 1u);
        sLast = (old == (unsigned int)(B - 1)) ? 1 : 0;
    }
    __syncthreads();
    if (!sLast) return;

    if (t == 0) {
        __threadfence();
        float pose = 0.f, ms = 0.f, es = 0.f;
        int nv = 0;
        for (int bb = 0; bb < B; ++bb) {
            const float* res = ws + WS_RES + bb * 8;
            float sw = res[0], sc = res[1], se = res[2], cn = res[3];
            pose += res[4];
            if (cn >= 3.f) { nv++; ms += sc / (sw + 1e-8f); es += se / (sw + 1e-8f); }
        }
        float match = nv > 0 ? ms / (float)nv : 0.f;
        float epi   = nv > 0 ? es / (float)nv : 0.f;
        out[0] = pose * (1.f / (float)B) + 0.5f * match + 0.1f * epi;
    }
}

extern "C" void kernel_launch(void* const* d_in, const int* in_sizes, int n_in,
                              void* d_out, int out_size, void* d_ws, size_t ws_size,
                              hipStream_t stream) {
    const float* R_pred  = (const float*)d_in[0];
    const float* t_pred  = (const float*)d_in[1];
    const float* R_gt    = (const float*)d_in[2];
    const float* t_gt    = (const float*)d_in[3];
    const float* K       = (const float*)d_in[4];
    const float* kp1     = (const float*)d_in[5];
    const float* kp2     = (const float*)d_in[6];
    const float* matches = (const float*)d_in[7];
    float* out = (float*)d_out;
    float* ws  = (float*)d_ws;

    k1_fused<<<NBLK, 256, 0, stream>>>(matches, R_gt, t_gt, K, kp1, kp2, ws);
    k2_perb <<<B,    256, 0, stream>>>(matches, R_pred, t_pred, R_gt, t_gt, K, kp1, kp2, ws, out);
}